// Round 16
// baseline (124.410 us; speedup 1.0000x reference)
//
#include <hip/hip_runtime.h>
#include <hip/hip_fp16.h>
#include <math.h>

#define BATCH 32
#define NPIX 160
#define LDIM 128
#define OUT_SZ 150        // 160 - 11 + 1

#define THREADS 512
// 1824 fused work blocks (swizzled) + 1 KLD block
#define N_BLOCKS 1825
// LDS carve (float units):
//   HXY stage: 18*160 half2 = 2880 fl (11.5 KB)
//   RD at 2880: 16*5*2*38 half2 = 3040 fl (12.2 KB)
//   VH at 5920: 5 planes x 1296 half = 3240 fl (13.0 KB)
#define RD_OFF 2880
#define VH_OFF 5920
#define SMEM_FLOATS 9160   // 36.6 KB -> 4 blocks/CU

// e^{-i*2pi*k/12}; entries 0 / ±0.5 / ±0.866 / ±1 -> FMAs fold at compile time
__device__ constexpr float TWC[12] = { 1.f, 0.86602540f, 0.5f, 0.f, -0.5f, -0.86602540f,
                                      -1.f,-0.86602540f,-0.5f, 0.f,  0.5f,  0.86602540f};
__device__ constexpr float TWS[12] = { 0.f,-0.5f,-0.86602540f,-1.f,-0.86602540f,-0.5f,
                                       0.f, 0.5f, 0.86602540f, 1.f, 0.86602540f, 0.5f};

__device__ constexpr float GW[11] = {0.00102838f, 0.00759876f, 0.03600076f, 0.10936070f,
                                     0.21300554f, 0.26601172f, 0.21300554f, 0.10936070f,
                                     0.03600076f, 0.00759876f, 0.00102838f};

// minimax atan poly, max err ~1e-6 rad (validated R7/R9-R15, absmax 0.0)
__device__ __forceinline__ float fast_atan2f(float y, float x) {
    float ax = fabsf(x), ay = fabsf(y);
    float mx = fmaxf(ax, ay), mn = fminf(ax, ay);
    float z = mn / mx;
    float z2 = z * z;
    float p = fmaf(z2, -0.01172120f, 0.05265332f);
    p = fmaf(z2, p, -0.11643287f);
    p = fmaf(z2, p, 0.19354346f);
    p = fmaf(z2, p, -0.33262347f);
    p = fmaf(z2, p, 0.99997726f);
    p = p * z;
    if (ay > ax) p = 1.57079632679489662f - p;
    if (x < 0.f) p = 3.14159265358979323f - p;
    return (y < 0.f) ? -p : p;
}

// extract channel C of 4 consecutive NHWC pixels held in 3 float4s (wave-uniform c)
__device__ __forceinline__ float4 extract_c(float4 f0, float4 f1, float4 f2, int c) {
    if (c == 0) return make_float4(f0.x, f0.w, f1.z, f2.y);
    if (c == 1) return make_float4(f0.y, f1.x, f1.w, f2.z);
    return make_float4(f0.z, f1.y, f2.x, f2.w);
}

__global__ __launch_bounds__(THREADS) void work_kernel(const float* __restrict__ xin,
                                                       const float* __restrict__ xout,
                                                       const float* __restrict__ mean,
                                                       const float* __restrict__ logvar,
                                                       float* __restrict__ out) {
    __shared__ __align__(16) float SMEM[SMEM_FLOATS];
    __shared__ float sm8[8];
    const int tid = threadIdx.x;
    const int gid = blockIdx.x;
    float acc = 0.f;

    if (gid == 1824) {
        // ---- KLD block ----
        float a = 0.f;
        for (int i = tid; i < BATCH * LDIM; i += THREADS) {
            float m = mean[i], lv = logvar[i];
            a += -0.5f * (1.f + lv - expf(lv) - m * m) * (1.f / 32.f);
        }
        #pragma unroll
        for (int o = 32; o > 0; o >>= 1) a += __shfl_down(a, o, 64);
        if ((tid & 63) == 0) sm8[tid >> 6] = a;
        __syncthreads();
        if (tid == 0) {
            float s = sm8[0];
            #pragma unroll
            for (int i = 1; i < 8; ++i) s += sm8[i];
            atomicAdd(out, s);
        }
        return;
    }

    // XCD-aware swizzle: channel-siblings (same b,tile; c=0,1,2) get gids differing
    // by 8 -> same gid%8 -> same XCD under round-robin dispatch -> shared L2 lines.
    int within = gid % 24;
    int group  = gid / 24;            // 0..75
    int c      = within / 8;
    int slot   = within % 8;
    int pair   = group * 8 + slot;    // 0..607
    int b      = pair / 19;
    int tile   = pair % 19;
    int r0 = tile * 8;

    __half2* HXY = (__half2*)SMEM;                 // [rr 0..17][col] = (x, y)
    __half2* RD  = (__half2*)(SMEM + RD_OFF);      // [r][vv][img][pc]
    __half*  VH  = (__half*)(SMEM + VH_OFF);       // [p][orow*160+col], 1296/plane

    // ---- stage: 720 tasks (rr, colq); NHWC both imgs, extract c, pack half2 ----
    for (int t = tid; t < 720; t += THREADS) {
        int rr = t / 40;
        int cq = t % 40;
        int row = r0 + rr;
        float4 xa = make_float4(0.f, 0.f, 0.f, 0.f);
        float4 xb = make_float4(0.f, 0.f, 0.f, 0.f);
        if (row < NPIX) {
            size_t off = ((size_t)(b * 160 + row) * 160 + cq * 4) * 3;
            const float4* qa = (const float4*)(xin + off);
            const float4* qb = (const float4*)(xout + off);
            float4 a0 = qa[0], a1 = qa[1], a2 = qa[2];
            float4 b0 = qb[0], b1 = qb[1], b2 = qb[2];
            xa = extract_c(a0, a1, a2, c);
            xb = extract_c(b0, b1, b2, c);
        }
        __half2 h[4] __attribute__((aligned(16)));
        h[0] = __floats2half2_rn(xa.x, xb.x);
        h[1] = __floats2half2_rn(xa.y, xb.y);
        h[2] = __floats2half2_rn(xa.z, xb.z);
        h[3] = __floats2half2_rn(xa.w, xb.w);
        *(float4*)&HXY[rr * 160 + cq * 4] = *(float4*)h;
    }
    __syncthreads();

    // ---- stft phase A: 608 tasks (r 0..15, pc); both images; real-input symmetry ----
    for (int t = tid; t < 608; t += THREADS) {
        int pc = t % 38;
        int r  = t / 38;
        float4 raw[3];
        raw[0] = *(const float4*)&HXY[r * 160 + pc * 4];
        raw[1] = *(const float4*)&HXY[r * 160 + pc * 4 + 4];
        raw[2] = *(const float4*)&HXY[r * 160 + pc * 4 + 8];
        const __half2* hp = (const __half2*)raw;
        float xa[12], xb[12];
        #pragma unroll
        for (int j = 0; j < 12; ++j) {
            float2 xy = __half22float2(hp[j]);
            xa[j] = xy.x; xb[j] = xy.y;
        }
        #pragma unroll
        for (int img = 0; img < 2; ++img) {
            const float* x = img ? xb : xa;
            float ev[5] = {x[1]+x[11], x[2]+x[10], x[3]+x[9], x[4]+x[8], x[5]+x[7]};
            float ov[5] = {x[1]-x[11], x[2]-x[10], x[3]-x[9], x[4]-x[8], x[5]-x[7]};
            #pragma unroll
            for (int vv = 0; vv < 5; ++vv) {
                int v = vv + 1;
                float re = x[0] + ((v & 1) ? -x[6] : x[6]);
                float im = 0.f;
                #pragma unroll
                for (int j = 1; j <= 5; ++j) {
                    int kk = (v * j) % 12;           // compile-time
                    re = fmaf(ev[j-1], TWC[kk], re);
                    im = fmaf(ov[j-1], TWS[kk], im);
                }
                RD[((r * 5 + vv) * 2 + img) * 38 + pc] = __floats2half2_rn(re, im);
            }
        }
    }
    __syncthreads();

    // ---- combined phase: stft-B (t<380) || ssim-V (t>=380); disjoint LDS regions ----
    for (int t = tid; t < 700; t += THREADS) {
        if (t < 380) {
            int pc = t % 38;
            int vv = (t / 38) % 5;
            int g  = t / 190;
            float FR0[5] = {0,0,0,0,0}, FI0[5] = {0,0,0,0,0};
            float FR1[5] = {0,0,0,0,0}, FI1[5] = {0,0,0,0,0};
            #pragma unroll
            for (int i = 0; i < 6; ++i) {
                int rlo = 4 * g + i, rhi = rlo + 6;
                float2 a0 = __half22float2(RD[((rlo * 5 + vv) * 2 + 0) * 38 + pc]);
                float2 a6 = __half22float2(RD[((rhi * 5 + vv) * 2 + 0) * 38 + pc]);
                float2 b0 = __half22float2(RD[((rlo * 5 + vv) * 2 + 1) * 38 + pc]);
                float2 b6 = __half22float2(RD[((rhi * 5 + vv) * 2 + 1) * 38 + pc]);
                float spR0 = a0.x + a6.x, spI0 = a0.y + a6.y;
                float smR0 = a0.x - a6.x, smI0 = a0.y - a6.y;
                float spR1 = b0.x + b6.x, spI1 = b0.y + b6.y;
                float smR1 = b0.x - b6.x, smI1 = b0.y - b6.y;
                #pragma unroll
                for (int uu = 0; uu < 5; ++uu) {
                    int u = uu + 1;
                    int kk = (u * i) % 12;               // compile-time twiddle
                    float cu = TWC[kk], su = TWS[kk];
                    float sR0 = (u & 1) ? smR0 : spR0, sI0 = (u & 1) ? smI0 : spI0;
                    float sR1 = (u & 1) ? smR1 : spR1, sI1 = (u & 1) ? smI1 : spI1;
                    FR0[uu] = fmaf(cu, sR0, fmaf(-su, sI0, FR0[uu]));
                    FI0[uu] = fmaf(cu, sI0, fmaf( su, sR0, FI0[uu]));
                    FR1[uu] = fmaf(cu, sR1, fmaf(-su, sI1, FR1[uu]));
                    FI1[uu] = fmaf(cu, sI1, fmaf( su, sR1, FI1[uu]));
                }
            }
            float sacc = 0.f;
            #pragma unroll
            for (int uu = 0; uu < 5; ++uu) {
                float aI = fast_atan2f(FI0[uu], FR0[uu] + 1e-8f);
                float aO = fast_atan2f(FI1[uu], FR1[uu] + 1e-8f);
                float mI = sqrtf(FR0[uu] * FR0[uu] + FI0[uu] * FI0[uu]);
                float mO = sqrtf(FR1[uu] * FR1[uu] + FI1[uu] * FI1[uu]);
                float ff = (float)((uu + 1) * (vv + 1)) * 0.04f;
                sacc += ff * (fabsf(aO - aI) + fabsf(mO - mI));
            }
            acc += sacc * (1e-4f / 32.f);
        } else {
            int tv = t - 380;                       // 0..319
            int orow = tv / 40;
            int cbase = (tv % 40) * 4;
            float ax[4] = {0,0,0,0}, ay[4] = {0,0,0,0};
            float axx[4] = {0,0,0,0}, ayy[4] = {0,0,0,0}, axy[4] = {0,0,0,0};
            #pragma unroll
            for (int kk = 0; kk < 11; ++kk) {
                float4 raw = *(const float4*)&HXY[(orow + kk) * 160 + cbase];
                const __half2* hp = (const __half2*)&raw;
                float wg = GW[kk];
                #pragma unroll
                for (int o = 0; o < 4; ++o) {
                    float2 xy = __half22float2(hp[o]);
                    ax[o]  += wg * xy.x;          ay[o]  += wg * xy.y;
                    axx[o] += wg * (xy.x * xy.x); ayy[o] += wg * (xy.y * xy.y);
                    axy[o] += wg * (xy.x * xy.y);
                }
            }
            int bh = orow * 160 + cbase;           // half-index within plane
            __half2 w0, w1;
            w0 = __floats2half2_rn(ax[0],  ax[1]);  w1 = __floats2half2_rn(ax[2],  ax[3]);
            *(__half2*)&VH[0 * 1296 + bh] = w0;     *(__half2*)&VH[0 * 1296 + bh + 2] = w1;
            w0 = __floats2half2_rn(ay[0],  ay[1]);  w1 = __floats2half2_rn(ay[2],  ay[3]);
            *(__half2*)&VH[1 * 1296 + bh] = w0;     *(__half2*)&VH[1 * 1296 + bh + 2] = w1;
            w0 = __floats2half2_rn(axx[0], axx[1]); w1 = __floats2half2_rn(axx[2], axx[3]);
            *(__half2*)&VH[2 * 1296 + bh] = w0;     *(__half2*)&VH[2 * 1296 + bh + 2] = w1;
            w0 = __floats2half2_rn(ayy[0], ayy[1]); w1 = __floats2half2_rn(ayy[2], ayy[3]);
            *(__half2*)&VH[3 * 1296 + bh] = w0;     *(__half2*)&VH[3 * 1296 + bh + 2] = w1;
            w0 = __floats2half2_rn(axy[0], axy[1]); w1 = __floats2half2_rn(axy[2], axy[3]);
            *(__half2*)&VH[4 * 1296 + bh] = w0;     *(__half2*)&VH[4 * 1296 + bh + 2] = w1;
        }
    }
    __syncthreads();

    // ---- ssim phase H: 600 tasks (8 orows x 75 col-pairs); half2 window reads ----
    {
        float hacc = 0.f;
        for (int t = tid; t < 600; t += THREADS) {
            int orow = t / 75;
            int oc = (t % 75) * 2;                 // even -> half2-aligned windows
            float st[5][2];
            #pragma unroll
            for (int p = 0; p < 5; ++p) {
                float vals[12];
                const __half2* vp = (const __half2*)&VH[p * 1296 + orow * 160 + oc];
                #pragma unroll
                for (int j = 0; j < 6; ++j) {
                    float2 f = __half22float2(vp[j]);
                    vals[2*j] = f.x; vals[2*j+1] = f.y;
                }
                float s0 = 0.f, s1 = 0.f;
                #pragma unroll
                for (int kk = 0; kk < 11; ++kk) {
                    s0 += GW[kk] * vals[kk];
                    s1 += GW[kk] * vals[kk + 1];
                }
                st[p][0] = s0; st[p][1] = s1;
            }
            const float c1 = 1e-4f, c2 = 9e-4f;
            if (r0 + orow < OUT_SZ) {
                #pragma unroll
                for (int o = 0; o < 2; ++o) {
                    float mx = st[0][o], my = st[1][o];
                    float vx = st[2][o] - mx * mx;
                    float vy = st[3][o] - my * my;
                    float cv = st[4][o] - mx * my;
                    float lum = (2.f * mx * my + c1) / (mx * mx + my * my + c1);
                    float cs  = (2.f * cv + c2) / (vx + vy + c2);
                    hacc += lum * cs;
                }
            }
        }
        acc += hacc * (1.f / (32.f * 150.f * 150.f * 3.f));
    }

    // ---- block reduce (8 waves) -> one device-scope atomic per block ----
    #pragma unroll
    for (int o = 32; o > 0; o >>= 1) acc += __shfl_down(acc, o, 64);
    if ((tid & 63) == 0) sm8[tid >> 6] = acc;
    __syncthreads();
    if (tid == 0) {
        float s = sm8[0];
        #pragma unroll
        for (int i = 1; i < 8; ++i) s += sm8[i];
        atomicAdd(out, s);
    }
}

extern "C" void kernel_launch(void* const* d_in, const int* in_sizes, int n_in,
                              void* d_out, int out_size, void* d_ws, size_t ws_size,
                              hipStream_t stream) {
    const float* mean   = (const float*)d_in[0];
    const float* logvar = (const float*)d_in[1];
    const float* xin    = (const float*)d_in[2];
    const float* xout   = (const float*)d_in[3];
    float* out = (float*)d_out;

    hipMemsetAsync(out, 0, sizeof(float), stream);   // graph-capturable memset node
    work_kernel<<<N_BLOCKS, THREADS, 0, stream>>>(xin, xout, mean, logvar, out);
}

// Round 17
// 124.113 us; speedup vs baseline: 1.0024x; 1.0024x over previous
//
#include <hip/hip_runtime.h>
#include <hip/hip_fp16.h>
#include <math.h>

#define BATCH 32
#define NPIX 160
#define LDIM 128
#define OUT_SZ 150        // 160 - 11 + 1

#define THREADS 512
// 1824 fused work blocks (swizzled) + 1 KLD block
#define N_BLOCKS 1825
// LDS carve (float units):
//   HXY stage: 18*160 half2 = 2880 fl (11.5 KB)
//   RD at 2880: 16*5*2*38 half2 = 3040 fl (12.2 KB)
//   VH at 5920: 5 planes x 1296 half = 3240 fl (13.0 KB)
#define RD_OFF 2880
#define VH_OFF 5920
#define SMEM_FLOATS 9160   // 36.6 KB -> 4 blocks/CU

// e^{-i*2pi*k/12}; entries 0 / ±0.5 / ±0.866 / ±1 -> FMAs fold at compile time
__device__ constexpr float TWC[12] = { 1.f, 0.86602540f, 0.5f, 0.f, -0.5f, -0.86602540f,
                                      -1.f,-0.86602540f,-0.5f, 0.f,  0.5f,  0.86602540f};
__device__ constexpr float TWS[12] = { 0.f,-0.5f,-0.86602540f,-1.f,-0.86602540f,-0.5f,
                                       0.f, 0.5f, 0.86602540f, 1.f, 0.86602540f, 0.5f};

__device__ constexpr float GW[11] = {0.00102838f, 0.00759876f, 0.03600076f, 0.10936070f,
                                     0.21300554f, 0.26601172f, 0.21300554f, 0.10936070f,
                                     0.03600076f, 0.00759876f, 0.00102838f};

// minimax atan poly, max err ~1e-6 rad (validated R7/R9-R16, absmax 0.0)
__device__ __forceinline__ float fast_atan2f(float y, float x) {
    float ax = fabsf(x), ay = fabsf(y);
    float mx = fmaxf(ax, ay), mn = fminf(ax, ay);
    float z = mn / mx;
    float z2 = z * z;
    float p = fmaf(z2, -0.01172120f, 0.05265332f);
    p = fmaf(z2, p, -0.11643287f);
    p = fmaf(z2, p, 0.19354346f);
    p = fmaf(z2, p, -0.33262347f);
    p = fmaf(z2, p, 0.99997726f);
    p = p * z;
    if (ay > ax) p = 1.57079632679489662f - p;
    if (x < 0.f) p = 3.14159265358979323f - p;
    return (y < 0.f) ? -p : p;
}

// extract channel C of 4 consecutive NHWC pixels held in 3 float4s (wave-uniform c)
__device__ __forceinline__ float4 extract_c(float4 f0, float4 f1, float4 f2, int c) {
    if (c == 0) return make_float4(f0.x, f0.w, f1.z, f2.y);
    if (c == 1) return make_float4(f0.y, f1.x, f1.w, f2.z);
    return make_float4(f0.z, f1.y, f2.x, f2.w);
}

__global__ __launch_bounds__(THREADS) void work_kernel(const float* __restrict__ xin,
                                                       const float* __restrict__ xout,
                                                       const float* __restrict__ mean,
                                                       const float* __restrict__ logvar,
                                                       float* __restrict__ out) {
    __shared__ __align__(16) float SMEM[SMEM_FLOATS];
    __shared__ float sm8[8];
    const int tid = threadIdx.x;
    const int gid = blockIdx.x;
    float acc = 0.f;

    if (gid == 1824) {
        // ---- KLD block ----
        float a = 0.f;
        for (int i = tid; i < BATCH * LDIM; i += THREADS) {
            float m = mean[i], lv = logvar[i];
            a += -0.5f * (1.f + lv - expf(lv) - m * m) * (1.f / 32.f);
        }
        #pragma unroll
        for (int o = 32; o > 0; o >>= 1) a += __shfl_down(a, o, 64);
        if ((tid & 63) == 0) sm8[tid >> 6] = a;
        __syncthreads();
        if (tid == 0) {
            float s = sm8[0];
            #pragma unroll
            for (int i = 1; i < 8; ++i) s += sm8[i];
            atomicAdd(out, s);
        }
        return;
    }

    // XCD-aware swizzle: channel-siblings (same b,tile; c=0,1,2) get gids differing
    // by 8 -> same gid%8 -> same XCD under round-robin dispatch -> shared L2 lines.
    int within = gid % 24;
    int group  = gid / 24;            // 0..75
    int c      = within / 8;
    int slot   = within % 8;
    int pair   = group * 8 + slot;    // 0..607
    int b      = pair / 19;
    int tile   = pair % 19;
    int r0 = tile * 8;

    __half2* HXY = (__half2*)SMEM;                 // [rr 0..17][col] = (x, y)
    __half2* RD  = (__half2*)(SMEM + RD_OFF);      // [r][vv][img][pc]
    __half*  VH  = (__half*)(SMEM + VH_OFF);       // [p][orow*160+col], 1296/plane

    // ---- stage: 720 tasks (rr, colq); NHWC both imgs, extract c, pack half2 ----
    for (int t = tid; t < 720; t += THREADS) {
        int rr = t / 40;
        int cq = t % 40;
        int row = r0 + rr;
        float4 xa = make_float4(0.f, 0.f, 0.f, 0.f);
        float4 xb = make_float4(0.f, 0.f, 0.f, 0.f);
        if (row < NPIX) {
            size_t off = ((size_t)(b * 160 + row) * 160 + cq * 4) * 3;
            const float4* qa = (const float4*)(xin + off);
            const float4* qb = (const float4*)(xout + off);
            float4 a0 = qa[0], a1 = qa[1], a2 = qa[2];
            float4 b0 = qb[0], b1 = qb[1], b2 = qb[2];
            xa = extract_c(a0, a1, a2, c);
            xb = extract_c(b0, b1, b2, c);
        }
        __half2 h[4] __attribute__((aligned(16)));
        h[0] = __floats2half2_rn(xa.x, xb.x);
        h[1] = __floats2half2_rn(xa.y, xb.y);
        h[2] = __floats2half2_rn(xa.z, xb.z);
        h[3] = __floats2half2_rn(xa.w, xb.w);
        *(float4*)&HXY[rr * 160 + cq * 4] = *(float4*)h;
    }
    __syncthreads();

    // ---- phase 1: ssim-V (t<320) || stft-A (t>=320) — independent given HXY ----
    for (int t = tid; t < 928; t += THREADS) {
        if (t < 320) {
            // ssim vertical 11-tap -> VH planes (fp16)
            int orow = t / 40;
            int cbase = (t % 40) * 4;
            float ax[4] = {0,0,0,0}, ay[4] = {0,0,0,0};
            float axx[4] = {0,0,0,0}, ayy[4] = {0,0,0,0}, axy[4] = {0,0,0,0};
            #pragma unroll
            for (int kk = 0; kk < 11; ++kk) {
                float4 raw = *(const float4*)&HXY[(orow + kk) * 160 + cbase];
                const __half2* hp = (const __half2*)&raw;
                float wg = GW[kk];
                #pragma unroll
                for (int o = 0; o < 4; ++o) {
                    float2 xy = __half22float2(hp[o]);
                    ax[o]  += wg * xy.x;          ay[o]  += wg * xy.y;
                    axx[o] += wg * (xy.x * xy.x); ayy[o] += wg * (xy.y * xy.y);
                    axy[o] += wg * (xy.x * xy.y);
                }
            }
            int bh = orow * 160 + cbase;
            __half2 w0, w1;
            w0 = __floats2half2_rn(ax[0],  ax[1]);  w1 = __floats2half2_rn(ax[2],  ax[3]);
            *(__half2*)&VH[0 * 1296 + bh] = w0;     *(__half2*)&VH[0 * 1296 + bh + 2] = w1;
            w0 = __floats2half2_rn(ay[0],  ay[1]);  w1 = __floats2half2_rn(ay[2],  ay[3]);
            *(__half2*)&VH[1 * 1296 + bh] = w0;     *(__half2*)&VH[1 * 1296 + bh + 2] = w1;
            w0 = __floats2half2_rn(axx[0], axx[1]); w1 = __floats2half2_rn(axx[2], axx[3]);
            *(__half2*)&VH[2 * 1296 + bh] = w0;     *(__half2*)&VH[2 * 1296 + bh + 2] = w1;
            w0 = __floats2half2_rn(ayy[0], ayy[1]); w1 = __floats2half2_rn(ayy[2], ayy[3]);
            *(__half2*)&VH[3 * 1296 + bh] = w0;     *(__half2*)&VH[3 * 1296 + bh + 2] = w1;
            w0 = __floats2half2_rn(axy[0], axy[1]); w1 = __floats2half2_rn(axy[2], axy[3]);
            *(__half2*)&VH[4 * 1296 + bh] = w0;     *(__half2*)&VH[4 * 1296 + bh + 2] = w1;
        } else {
            // stft row-DFT (both images), real-input symmetry
            int ta = t - 320;                      // 0..607
            int pc = ta % 38;
            int r  = ta / 38;
            float4 raw[3];
            raw[0] = *(const float4*)&HXY[r * 160 + pc * 4];
            raw[1] = *(const float4*)&HXY[r * 160 + pc * 4 + 4];
            raw[2] = *(const float4*)&HXY[r * 160 + pc * 4 + 8];
            const __half2* hp = (const __half2*)raw;
            float xa[12], xb[12];
            #pragma unroll
            for (int j = 0; j < 12; ++j) {
                float2 xy = __half22float2(hp[j]);
                xa[j] = xy.x; xb[j] = xy.y;
            }
            #pragma unroll
            for (int img = 0; img < 2; ++img) {
                const float* x = img ? xb : xa;
                float ev[5] = {x[1]+x[11], x[2]+x[10], x[3]+x[9], x[4]+x[8], x[5]+x[7]};
                float ov[5] = {x[1]-x[11], x[2]-x[10], x[3]-x[9], x[4]-x[8], x[5]-x[7]};
                #pragma unroll
                for (int vv = 0; vv < 5; ++vv) {
                    int v = vv + 1;
                    float re = x[0] + ((v & 1) ? -x[6] : x[6]);
                    float im = 0.f;
                    #pragma unroll
                    for (int j = 1; j <= 5; ++j) {
                        int kk = (v * j) % 12;           // compile-time
                        re = fmaf(ev[j-1], TWC[kk], re);
                        im = fmaf(ov[j-1], TWS[kk], im);
                    }
                    RD[((r * 5 + vv) * 2 + img) * 38 + pc] = __floats2half2_rn(re, im);
                }
            }
        }
    }
    __syncthreads();

    // ---- phase 2: stft-B (t<380) || ssim-H (t>=380) — B reads RD, H reads VH ----
    for (int t = tid; t < 980; t += THREADS) {
        if (t < 380) {
            int pc = t % 38;
            int vv = (t / 38) % 5;
            int g  = t / 190;
            float FR0[5] = {0,0,0,0,0}, FI0[5] = {0,0,0,0,0};
            float FR1[5] = {0,0,0,0,0}, FI1[5] = {0,0,0,0,0};
            #pragma unroll
            for (int i = 0; i < 6; ++i) {
                int rlo = 4 * g + i, rhi = rlo + 6;
                float2 a0 = __half22float2(RD[((rlo * 5 + vv) * 2 + 0) * 38 + pc]);
                float2 a6 = __half22float2(RD[((rhi * 5 + vv) * 2 + 0) * 38 + pc]);
                float2 b0 = __half22float2(RD[((rlo * 5 + vv) * 2 + 1) * 38 + pc]);
                float2 b6 = __half22float2(RD[((rhi * 5 + vv) * 2 + 1) * 38 + pc]);
                float spR0 = a0.x + a6.x, spI0 = a0.y + a6.y;
                float smR0 = a0.x - a6.x, smI0 = a0.y - a6.y;
                float spR1 = b0.x + b6.x, spI1 = b0.y + b6.y;
                float smR1 = b0.x - b6.x, smI1 = b0.y - b6.y;
                #pragma unroll
                for (int uu = 0; uu < 5; ++uu) {
                    int u = uu + 1;
                    int kk = (u * i) % 12;               // compile-time twiddle
                    float cu = TWC[kk], su = TWS[kk];
                    float sR0 = (u & 1) ? smR0 : spR0, sI0 = (u & 1) ? smI0 : spI0;
                    float sR1 = (u & 1) ? smR1 : spR1, sI1 = (u & 1) ? smI1 : spI1;
                    FR0[uu] = fmaf(cu, sR0, fmaf(-su, sI0, FR0[uu]));
                    FI0[uu] = fmaf(cu, sI0, fmaf( su, sR0, FI0[uu]));
                    FR1[uu] = fmaf(cu, sR1, fmaf(-su, sI1, FR1[uu]));
                    FI1[uu] = fmaf(cu, sI1, fmaf( su, sR1, FI1[uu]));
                }
            }
            float sacc = 0.f;
            #pragma unroll
            for (int uu = 0; uu < 5; ++uu) {
                float aI = fast_atan2f(FI0[uu], FR0[uu] + 1e-8f);
                float aO = fast_atan2f(FI1[uu], FR1[uu] + 1e-8f);
                float mI = sqrtf(FR0[uu] * FR0[uu] + FI0[uu] * FI0[uu]);
                float mO = sqrtf(FR1[uu] * FR1[uu] + FI1[uu] * FI1[uu]);
                float ff = (float)((uu + 1) * (vv + 1)) * 0.04f;
                sacc += ff * (fabsf(aO - aI) + fabsf(mO - mI));
            }
            acc += sacc * (1e-4f / 32.f);
        } else {
            int th = t - 380;                      // 0..599
            int orow = th / 75;
            int oc = (th % 75) * 2;                // even -> half2-aligned windows
            float st[5][2];
            #pragma unroll
            for (int p = 0; p < 5; ++p) {
                float vals[12];
                const __half2* vp = (const __half2*)&VH[p * 1296 + orow * 160 + oc];
                #pragma unroll
                for (int j = 0; j < 6; ++j) {
                    float2 f = __half22float2(vp[j]);
                    vals[2*j] = f.x; vals[2*j+1] = f.y;
                }
                float s0 = 0.f, s1 = 0.f;
                #pragma unroll
                for (int kk = 0; kk < 11; ++kk) {
                    s0 += GW[kk] * vals[kk];
                    s1 += GW[kk] * vals[kk + 1];
                }
                st[p][0] = s0; st[p][1] = s1;
            }
            const float c1 = 1e-4f, c2 = 9e-4f;
            if (r0 + orow < OUT_SZ) {
                float hacc = 0.f;
                #pragma unroll
                for (int o = 0; o < 2; ++o) {
                    float mx = st[0][o], my = st[1][o];
                    float vx = st[2][o] - mx * mx;
                    float vy = st[3][o] - my * my;
                    float cv = st[4][o] - mx * my;
                    float lum = (2.f * mx * my + c1) / (mx * mx + my * my + c1);
                    float cs  = (2.f * cv + c2) / (vx + vy + c2);
                    hacc += lum * cs;
                }
                acc += hacc * (1.f / (32.f * 150.f * 150.f * 3.f));
            }
        }
    }

    // ---- block reduce (8 waves) -> one device-scope atomic per block ----
    #pragma unroll
    for (int o = 32; o > 0; o >>= 1) acc += __shfl_down(acc, o, 64);
    if ((tid & 63) == 0) sm8[tid >> 6] = acc;
    __syncthreads();
    if (tid == 0) {
        float s = sm8[0];
        #pragma unroll
        for (int i = 1; i < 8; ++i) s += sm8[i];
        atomicAdd(out, s);
    }
}

extern "C" void kernel_launch(void* const* d_in, const int* in_sizes, int n_in,
                              void* d_out, int out_size, void* d_ws, size_t ws_size,
                              hipStream_t stream) {
    const float* mean   = (const float*)d_in[0];
    const float* logvar = (const float*)d_in[1];
    const float* xin    = (const float*)d_in[2];
    const float* xout   = (const float*)d_in[3];
    float* out = (float*)d_out;

    hipMemsetAsync(out, 0, sizeof(float), stream);   // graph-capturable memset node
    work_kernel<<<N_BLOCKS, THREADS, 0, stream>>>(xin, xout, mean, logvar, out);
}